// Round 8
// baseline (264.691 us; speedup 1.0000x reference)
//
#include <hip/hip_runtime.h>

typedef unsigned short u16;
typedef __bf16 bf16;
typedef bf16 bf16x8 __attribute__((ext_vector_type(8)));
typedef float f32x4 __attribute__((ext_vector_type(4)));

#define S 2048
#define D 64
#define BATCH 4
#define SCL 0.022097086912079612f  /* 1/sqrt(2048) */

__device__ __forceinline__ u16 f2bf(float f) {
  union { float f; unsigned u; } v; v.f = f;
  return (u16)((v.u + 0x7FFFu + ((v.u >> 16) & 1u)) >> 16);
}

__device__ __forceinline__ void gld16(const u16* g, u16* l) {
  __builtin_amdgcn_global_load_lds(
      (const __attribute__((address_space(1))) unsigned int*)(const void*)g,
      (__attribute__((address_space(3))) unsigned int*)(void*)l, 16, 0, 0);
}

// ---- N1: fused pre. Q = W_Q@G == W'@x with W'[m,u] = suffix_{t>=u} W_Q[m,t]/(t+1).
// jobs: [0,512)    W' suffix-scan, 1 wave/row, float4-vectorized, loads prefetched
//       [512,2560) W_V -> bf16
//       [2560,2688) x -> xb (row-major) + xTb (transposed), bf16
//       [2688,3200) zero d_out (+ block 2688 zeros the sync flags)
__global__ void k_pre(const float* __restrict__ x,
                      const float* __restrict__ wq, const float* __restrict__ wv,
                      u16* __restrict__ wqp, u16* __restrict__ wvb,
                      u16* __restrict__ xb, u16* __restrict__ xTb,
                      float* __restrict__ out, int* __restrict__ cnt) {
  int bx = blockIdx.x, t = threadIdx.x;
  if (bx < 512) {                        // W' suffix scan (vectorized)
    int m = bx * 4 + (t >> 6);
    int l = t & 63;
    const float* row = wq + (size_t)m * S;
    u16* orow = wqp + (size_t)m * S;
    float4 f[8];
#pragma unroll
    for (int c = 0; c < 8; ++c) f[c] = *(const float4*)(row + c * 256 + l * 4);
#pragma unroll
    for (int c = 0; c < 8; ++c) {
      int base = c * 256 + l * 4;
      f[c].x /= (float)(base + 1); f[c].y /= (float)(base + 2);
      f[c].z /= (float)(base + 3); f[c].w /= (float)(base + 4);
    }
    float carry = 0.f;
#pragma unroll
    for (int c = 7; c >= 0; --c) {
      float4 v = f[c];
      float sl = v.x + v.y + v.z + v.w;
      float s = sl;
#pragma unroll
      for (int off = 1; off < 64; off <<= 1) {
        float o = __shfl_down(s, off);
        s += (l + off < 64) ? o : 0.f;
      }
      float tot = __shfl(s, 0);
      float excl = s - sl;               // sum over lanes above
      float s3 = v.w, s2 = v.z + s3, s1 = v.y + s2, s0 = v.x + s1;
      union { u16 q[4]; ushort4 u4; } o;
      o.q[0] = f2bf(carry + excl + s0);
      o.q[1] = f2bf(carry + excl + s1);
      o.q[2] = f2bf(carry + excl + s2);
      o.q[3] = f2bf(carry + excl + s3);
      *(ushort4*)(orow + c * 256 + l * 4) = o.u4;
      carry += tot;
    }
  } else if (bx < 2560) {                // W_V convert
    size_t idx = ((size_t)(bx - 512) * 256 + t) * 8;
    const float* src = wv + idx;
    float4 a = *(const float4*)src;
    float4 b = *(const float4*)(src + 4);
    union { u16 s[8]; uint4 v; } u;
    u.s[0]=f2bf(a.x); u.s[1]=f2bf(a.y); u.s[2]=f2bf(a.z); u.s[3]=f2bf(a.w);
    u.s[4]=f2bf(b.x); u.s[5]=f2bf(b.y); u.s[6]=f2bf(b.z); u.s[7]=f2bf(b.w);
    *(uint4*)(wvb + idx) = u.v;
  } else if (bx < 2688) {                // x convert + transpose
    int job = (bx - 2560) * 4 + (t >> 6);
    int chunk = job >> 2, b = job & 3, d = t & 63;
    const float* xp = x + ((size_t)b * S + (size_t)chunk * 16) * D + d;
#pragma unroll
    for (int s = 0; s < 16; ++s) {
      float v = xp[(size_t)s * D];
      int sg = chunk * 16 + s;
      u16 h = f2bf(v);
      xb[((size_t)b * S + sg) * D + d] = h;
      xTb[((size_t)b * D + d) * S + sg] = h;
    }
  } else {                               // zero d_out (+ flags)
    if (bx == 2688 && t < 128) cnt[t] = 0;
    size_t i = (((size_t)(bx - 2688) * 256) + t) * 4;
    *(float4*)(out + i) = make_float4(0.f, 0.f, 0.f, 0.f);
  }
}

// ---- N2: GEMMs Q = W'@x, V = W_V@x (shared B-panel xTb). Tile 64M x 32N,
// 128 threads (2 waves x 32Mx32N), BK=64, 512 blocks = 2/CU.
__global__ __launch_bounds__(128) void k_wg(
    const u16* __restrict__ wqp, const u16* __restrict__ wvb,
    const u16* __restrict__ xTb,
    u16* __restrict__ Qb, u16* __restrict__ VTb) {
  __shared__ u16 Ab[2][64 * 64];  // 16 KB
  __shared__ u16 Bb[2][32 * 64];  // 8 KB
  int bx = blockIdx.x;            // nt*64 + mt*2 + mat : B-panel shared across 64
  int nt = bx >> 6, mm = bx & 63, mt = mm >> 1, mat = mm & 1;
  int t = threadIdx.x;
  int w = t >> 6, l = t & 63;
  int lr = l & 15, lg = l >> 4;
  const u16* A = (mat ? wvb : wqp) + (size_t)(mt * 64) * S;
  const u16* BT = xTb + (size_t)(nt * 32) * S;
  int rA = t >> 3;                 // 0..15: row within a 16-row issue
  int sb = t & 7;                  // 16B slot
  int swz = (sb ^ (rA & 7)) * 8;   // pre-swizzled source column
  const u16* Ag = A + (size_t)rA * S + swz;
  const u16* Bg = BT + (size_t)rA * S + swz;
  f32x4 acc[2][2] = {};

  auto stage = [&](int buf, int kt) {
#pragma unroll
    for (int i = 0; i < 4; ++i)
      gld16(Ag + kt * 64 + (size_t)i * 16 * S, &Ab[buf][i * 1024 + t * 8]);
#pragma unroll
    for (int i = 0; i < 2; ++i)
      gld16(Bg + kt * 64 + (size_t)i * 16 * S, &Bb[buf][i * 1024 + t * 8]);
  };

  stage(0, 0);
  __syncthreads();
  int buf = 0;
  for (int kt = 0; kt < 32; ++kt) {
    if (kt < 31) stage(buf ^ 1, kt + 1);
    bf16x8 af[2][2], bfv[2][2];
#pragma unroll
    for (int mf = 0; mf < 2; ++mf)
#pragma unroll
      for (int ks = 0; ks < 2; ++ks) {
        int row = w * 32 + mf * 16 + lr;
        af[mf][ks] = *(const bf16x8*)&Ab[buf][row * 64 + (((ks * 4 + lg) ^ (lr & 7)) * 8)];
      }
#pragma unroll
    for (int nf = 0; nf < 2; ++nf)
#pragma unroll
      for (int ks = 0; ks < 2; ++ks) {
        int row = nf * 16 + lr;
        bfv[nf][ks] = *(const bf16x8*)&Bb[buf][row * 64 + (((ks * 4 + lg) ^ (lr & 7)) * 8)];
      }
#pragma unroll
    for (int ks = 0; ks < 2; ++ks)
#pragma unroll
      for (int mf = 0; mf < 2; ++mf)
#pragma unroll
        for (int nf = 0; nf < 2; ++nf)
          acc[mf][nf] = __builtin_amdgcn_mfma_f32_16x16x32_bf16(af[mf][ks], bfv[nf][ks], acc[mf][nf], 0, 0, 0);
    __syncthreads();
    buf ^= 1;
  }
#pragma unroll
  for (int mf = 0; mf < 2; ++mf) {
    int mbase = mt * 64 + w * 32 + mf * 16 + lg * 4;
#pragma unroll
    for (int nf = 0; nf < 2; ++nf) {
      int n = nt * 32 + nf * 16 + lr;
      int b = n >> 6, d = n & 63;
      if (mat == 0) {
#pragma unroll
        for (int r = 0; r < 4; ++r)
          Qb[((size_t)b * S + mbase + r) * D + d] = f2bf(acc[mf][nf][r]);
      } else {
        union { u16 s[4]; ushort4 v; } u;
#pragma unroll
        for (int r = 0; r < 4; ++r) u.s[r] = f2bf(acc[mf][nf][r]);
        *(ushort4*)&VTb[((size_t)b * D + d) * S + mbase] = u.v;
      }
    }
  }
}

// ---- N3: FUSED stats + out with cross-block flag sync.
// bx < 128: stats role (jg = bx; heavy-first since low jg = most i's).
//   Z_j = sum_{i>=j, sc>1} exp(sc*SCL); writes rz, then release-adds cnt[b][jg>>2].
// bx >= 128: out role, (it,jc) heavy-first. Per jt: QK MFMAs FIRST (overlaps
//   producer), then acquire-spin on cnt[b][jt]==4, exp/normalize, PV.
// All 1088 blocks co-resident (<=2048 capacity) -> spin is deadlock-free.
__global__ __launch_bounds__(256) void k_su(
    const u16* __restrict__ xb, const u16* __restrict__ Qb, const u16* __restrict__ VTb,
    float* __restrict__ rzbuf, int* __restrict__ cnt, float* __restrict__ out) {
  __shared__ u16 Plds[4][16][72];
  __shared__ float zs[4][16];
  int bx = blockIdx.x, b = blockIdx.y;
  int tid = threadIdx.x;
  int w = tid >> 6, l = tid & 63;
  int lr = l & 15, lg = l >> 4;
  const u16* xbase = xb + (size_t)b * S * D;
  const u16* qbase = Qb + (size_t)b * S * D;

  if (bx < 128) {
    // ---------------- stats role ----------------
    int jg = bx;
    int j0 = jg * 16;
    bf16x8 xa0 = *(const bf16x8*)(xbase + (size_t)(j0 + lr) * D + lg * 8);
    bf16x8 xa1 = *(const bf16x8*)(xbase + (size_t)(j0 + lr) * D + 32 + lg * 8);
    float z[4] = {0.f, 0.f, 0.f, 0.f};
    for (int i16 = j0 + w * 16; i16 < S; i16 += 64) {
      bf16x8 q0 = *(const bf16x8*)(qbase + (size_t)(i16 + lr) * D + lg * 8);
      bf16x8 q1 = *(const bf16x8*)(qbase + (size_t)(i16 + lr) * D + 32 + lg * 8);
      f32x4 c = {};
      c = __builtin_amdgcn_mfma_f32_16x16x32_bf16(xa0, q0, c, 0, 0, 0);
      c = __builtin_amdgcn_mfma_f32_16x16x32_bf16(xa1, q1, c, 0, 0, 0);
      int i = i16 + lr;
#pragma unroll
      for (int r = 0; r < 4; ++r) {
        int j = j0 + lg * 4 + r;
        float sc = c[r];
        z[r] += (i >= j && sc > 1.0f) ? __expf(sc * SCL) : 0.f;
      }
    }
#pragma unroll
    for (int r = 0; r < 4; ++r) {
      z[r] += __shfl_xor(z[r], 1);
      z[r] += __shfl_xor(z[r], 2);
      z[r] += __shfl_xor(z[r], 4);
      z[r] += __shfl_xor(z[r], 8);
    }
    if (lr == 0) {
#pragma unroll
      for (int r = 0; r < 4; ++r) zs[w][lg * 4 + r] = z[r];
    }
    __syncthreads();
    if (tid < 16) {
      float zf = zs[0][tid] + zs[1][tid] + zs[2][tid] + zs[3][tid];
      rzbuf[(size_t)b * S + j0 + tid] = 1.0f / zf;
    }
    __threadfence();   // write back L2 so rz is device-visible
    if (tid == 0)
      __hip_atomic_fetch_add(&cnt[b * 32 + (jg >> 2)], 1,
                             __ATOMIC_RELEASE, __HIP_MEMORY_SCOPE_AGENT);
  } else {
    // ---------------- out role ----------------
    int obx = 143 - (bx - 128);  // heavy-first
    int it = 0, jc = 0, base = 0;
    for (int tt = 0; tt < 32; ++tt) {
      int nc = (tt + 4) >> 2;
      if (obx < base + nc) { it = tt; jc = obx - base; break; }
      base += nc;
    }
    int i0 = it * 64 + w * 16;
    const u16* vbase = VTb + (size_t)b * D * S;
    const float* rzb = rzbuf + (size_t)b * S;
    bf16x8 qa0 = *(const bf16x8*)(qbase + (size_t)(i0 + lr) * D + lg * 8);
    bf16x8 qa1 = *(const bf16x8*)(qbase + (size_t)(i0 + lr) * D + 32 + lg * 8);
    f32x4 acc[4] = {};
    int jt_end = min(jc * 4 + 4, it + 1);
    for (int jt = jc * 4; jt < jt_end; ++jt) {
      // scores FIRST (overlaps the stats producers)
      f32x4 c4[4];
#pragma unroll
      for (int js = 0; js < 4; ++js) {
        int j16 = jt * 64 + js * 16;
        bf16x8 xb0 = *(const bf16x8*)(xbase + (size_t)(j16 + lr) * D + lg * 8);
        bf16x8 xb1 = *(const bf16x8*)(xbase + (size_t)(j16 + lr) * D + 32 + lg * 8);
        f32x4 c = {};
        c = __builtin_amdgcn_mfma_f32_16x16x32_bf16(qa0, xb0, c, 0, 0, 0);
        c = __builtin_amdgcn_mfma_f32_16x16x32_bf16(qa1, xb1, c, 0, 0, 0);
        c4[js] = c;
      }
      // acquire rz for this jt
      if (tid == 0) {
        while (__hip_atomic_load(&cnt[b * 32 + jt], __ATOMIC_RELAXED,
                                 __HIP_MEMORY_SCOPE_AGENT) < 4)
          __builtin_amdgcn_s_sleep(2);
      }
      __syncthreads();
      __threadfence();   // invalidate L2 so rz loads are fresh
#pragma unroll
      for (int js = 0; js < 4; ++js) {
        int j = jt * 64 + js * 16 + lr;
        float rzj = rzb[j];
#pragma unroll
        for (int r = 0; r < 4; ++r) {
          int i = i0 + lg * 4 + r;
          float sc = c4[js][r];
          float wgt = (j <= i && sc > 1.0f) ? __expf(sc * SCL) * rzj : 0.f;
          Plds[w][lg * 4 + r][js * 16 + lr] = f2bf(wgt);
        }
      }
      asm volatile("s_waitcnt lgkmcnt(0)" ::: "memory");
#pragma unroll
      for (int kk = 0; kk < 2; ++kk) {
        bf16x8 pa = *(const bf16x8*)(&Plds[w][lr][kk * 32 + lg * 8]);
#pragma unroll
        for (int dt = 0; dt < 4; ++dt) {
          bf16x8 vbf = *(const bf16x8*)(vbase + (size_t)(dt * 16 + lr) * S + jt * 64 + kk * 32 + lg * 8);
          acc[dt] = __builtin_amdgcn_mfma_f32_16x16x32_bf16(pa, vbf, acc[dt], 0, 0, 0);
        }
      }
      asm volatile("s_waitcnt lgkmcnt(0)" ::: "memory");
    }
    float* obase = out + (size_t)b * S * D;
#pragma unroll
    for (int dt = 0; dt < 4; ++dt)
#pragma unroll
      for (int r = 0; r < 4; ++r) {
        int i = i0 + lg * 4 + r;
        atomicAdd(&obase[(size_t)i * D + dt * 16 + lr], acc[dt][r]);
      }
  }
}

extern "C" void kernel_launch(void* const* d_in, const int* in_sizes, int n_in,
                              void* d_out, int out_size, void* d_ws, size_t ws_size,
                              hipStream_t stream) {
  const float* x  = (const float*)d_in[0];
  const float* wq = (const float*)d_in[1];
  const float* wv = (const float*)d_in[2];
  float* out = (float*)d_out;
  char* ws = (char*)d_ws;
  size_t off = 0;
  auto alloc = [&](size_t bytes) -> void* {
    void* p = ws + off; off += (bytes + 255) & ~255ULL; return p;
  };
  u16* xb   = (u16*)alloc((size_t)BATCH * S * D * 2);
  u16* xTb  = (u16*)alloc((size_t)BATCH * S * D * 2);
  u16* Qb   = (u16*)alloc((size_t)BATCH * S * D * 2);
  u16* VTb  = (u16*)alloc((size_t)BATCH * S * D * 2);
  float* rzbuf = (float*)alloc((size_t)BATCH * S * 4);
  int*   cnt   = (int*)alloc((size_t)BATCH * 32 * 4);
  u16* wqp  = (u16*)alloc((size_t)S * S * 2);   // W' = W_Q @ L (suffix-scanned)
  u16* wvb  = (u16*)alloc((size_t)S * S * 2);

  k_pre<<<3200, 256, 0, stream>>>(x, wq, wv, wqp, wvb, xb, xTb, out, cnt);
  k_wg<<<512, 128, 0, stream>>>(wqp, wvb, xTb, Qb, VTb);
  k_su<<<dim3(272, BATCH), 256, 0, stream>>>(xb, Qb, VTb, rzbuf, cnt, out);
}

// Round 9
// 75.995 us; speedup vs baseline: 3.4830x; 3.4830x over previous
//
#include <hip/hip_runtime.h>

typedef unsigned short u16;
typedef __bf16 bf16;
typedef bf16 bf16x8 __attribute__((ext_vector_type(8)));
typedef float f32x4 __attribute__((ext_vector_type(4)));

#define S 2048
#define D 64
#define BATCH 4
#define SCL 0.022097086912079612f  /* 1/sqrt(2048) */

__device__ __forceinline__ u16 f2bf(float f) {
  union { float f; unsigned u; } v; v.f = f;
  return (u16)((v.u + 0x7FFFu + ((v.u >> 16) & 1u)) >> 16);
}

__device__ __forceinline__ void gld16(const u16* g, u16* l) {
  __builtin_amdgcn_global_load_lds(
      (const __attribute__((address_space(1))) unsigned int*)(const void*)g,
      (__attribute__((address_space(3))) unsigned int*)(void*)l, 16, 0, 0);
}

// ---- N1: fused pre. Q = W_Q@G == W'@x with W'[m,u] = suffix_{t>=u} W_Q[m,t]/(t+1).
// jobs: [0,512)    W' suffix-scan, 1 wave/row, float4-vectorized, loads prefetched
//       [512,2560) W_V -> bf16
//       [2560,2688) x -> xb (row-major) + xTb (transposed), bf16
//       [2688,3200) zero d_out
__global__ void k_pre(const float* __restrict__ x,
                      const float* __restrict__ wq, const float* __restrict__ wv,
                      u16* __restrict__ wqp, u16* __restrict__ wvb,
                      u16* __restrict__ xb, u16* __restrict__ xTb,
                      float* __restrict__ out) {
  int bx = blockIdx.x, t = threadIdx.x;
  if (bx < 512) {                        // W' suffix scan (vectorized)
    int m = bx * 4 + (t >> 6);
    int l = t & 63;
    const float* row = wq + (size_t)m * S;
    u16* orow = wqp + (size_t)m * S;
    float4 f[8];
#pragma unroll
    for (int c = 0; c < 8; ++c) f[c] = *(const float4*)(row + c * 256 + l * 4);
#pragma unroll
    for (int c = 0; c < 8; ++c) {
      int base = c * 256 + l * 4;
      f[c].x /= (float)(base + 1); f[c].y /= (float)(base + 2);
      f[c].z /= (float)(base + 3); f[c].w /= (float)(base + 4);
    }
    float carry = 0.f;
#pragma unroll
    for (int c = 7; c >= 0; --c) {
      float4 v = f[c];
      float sl = v.x + v.y + v.z + v.w;
      float s = sl;
#pragma unroll
      for (int off = 1; off < 64; off <<= 1) {
        float o = __shfl_down(s, off);
        s += (l + off < 64) ? o : 0.f;
      }
      float tot = __shfl(s, 0);
      float excl = s - sl;               // sum over lanes above
      float s3 = v.w, s2 = v.z + s3, s1 = v.y + s2, s0 = v.x + s1;
      union { u16 q[4]; ushort4 u4; } o;
      o.q[0] = f2bf(carry + excl + s0);
      o.q[1] = f2bf(carry + excl + s1);
      o.q[2] = f2bf(carry + excl + s2);
      o.q[3] = f2bf(carry + excl + s3);
      *(ushort4*)(orow + c * 256 + l * 4) = o.u4;
      carry += tot;
    }
  } else if (bx < 2560) {                // W_V convert
    size_t idx = ((size_t)(bx - 512) * 256 + t) * 8;
    const float* src = wv + idx;
    float4 a = *(const float4*)src;
    float4 b = *(const float4*)(src + 4);
    union { u16 s[8]; uint4 v; } u;
    u.s[0]=f2bf(a.x); u.s[1]=f2bf(a.y); u.s[2]=f2bf(a.z); u.s[3]=f2bf(a.w);
    u.s[4]=f2bf(b.x); u.s[5]=f2bf(b.y); u.s[6]=f2bf(b.z); u.s[7]=f2bf(b.w);
    *(uint4*)(wvb + idx) = u.v;
  } else if (bx < 2688) {                // x convert + transpose
    int job = (bx - 2560) * 4 + (t >> 6);
    int chunk = job >> 2, b = job & 3, d = t & 63;
    const float* xp = x + ((size_t)b * S + (size_t)chunk * 16) * D + d;
#pragma unroll
    for (int s = 0; s < 16; ++s) {
      float v = xp[(size_t)s * D];
      int sg = chunk * 16 + s;
      u16 h = f2bf(v);
      xb[((size_t)b * S + sg) * D + d] = h;
      xTb[((size_t)b * D + d) * S + sg] = h;
    }
  } else {                               // zero d_out
    size_t i = (((size_t)(bx - 2688) * 256) + t) * 4;
    *(float4*)(out + i) = make_float4(0.f, 0.f, 0.f, 0.f);
  }
}

// ---- N2: GEMMs Q = W'@x, V = W_V@x (shared B-panel xTb). Tile 64M x 32N,
// 128 threads (2 waves x 32Mx32N), BK=128 (16 K-steps: half the barrier
// drains of BK=64), 48 KB LDS, 512 blocks = 2/CU (capacity 3).
__global__ __launch_bounds__(128) void k_wg(
    const u16* __restrict__ wqp, const u16* __restrict__ wvb,
    const u16* __restrict__ xTb,
    u16* __restrict__ Qb, u16* __restrict__ VTb) {
  __shared__ u16 Ab[2][64 * 128];  // 32 KB
  __shared__ u16 Bb[2][32 * 128];  // 16 KB
  int bx = blockIdx.x;            // nt*64 + mt*2 + mat : B-panel shared across 64
  int nt = bx >> 6, mm = bx & 63, mt = mm >> 1, mat = mm & 1;
  int t = threadIdx.x;
  int w = t >> 6, l = t & 63;
  int lr = l & 15, lg = l >> 4;
  const u16* A = (mat ? wvb : wqp) + (size_t)(mt * 64) * S;
  const u16* BT = xTb + (size_t)(nt * 32) * S;
  int rA = t >> 4;                 // 0..7: row within an 8-row issue
  int sb = t & 15;                 // 16B slot within 256B row
  int swz = ((sb & 8) | ((sb & 7) ^ (rA & 7))) * 8;  // pre-swizzled source col
  const u16* Ag = A + (size_t)rA * S + swz;
  const u16* Bg = BT + (size_t)rA * S + swz;
  f32x4 acc[2][2] = {};

  auto stage = [&](int buf, int kt) {
#pragma unroll
    for (int i = 0; i < 8; ++i)
      gld16(Ag + kt * 128 + (size_t)i * 8 * S, &Ab[buf][i * 1024 + t * 8]);
#pragma unroll
    for (int i = 0; i < 4; ++i)
      gld16(Bg + kt * 128 + (size_t)i * 8 * S, &Bb[buf][i * 1024 + t * 8]);
  };

  stage(0, 0);
  __syncthreads();
  int buf = 0;
  for (int kt = 0; kt < 16; ++kt) {
    if (kt < 15) stage(buf ^ 1, kt + 1);
    bf16x8 af[2][4], bfv[2][4];
#pragma unroll
    for (int mf = 0; mf < 2; ++mf)
#pragma unroll
      for (int ks = 0; ks < 4; ++ks) {
        int row = w * 32 + mf * 16 + lr;
        int s = ks * 4 + lg;
        int col = ((s & 8) | ((s & 7) ^ (lr & 7))) * 8;
        af[mf][ks] = *(const bf16x8*)&Ab[buf][row * 128 + col];
      }
#pragma unroll
    for (int nf = 0; nf < 2; ++nf)
#pragma unroll
      for (int ks = 0; ks < 4; ++ks) {
        int row = nf * 16 + lr;
        int s = ks * 4 + lg;
        int col = ((s & 8) | ((s & 7) ^ (lr & 7))) * 8;
        bfv[nf][ks] = *(const bf16x8*)&Bb[buf][row * 128 + col];
      }
#pragma unroll
    for (int ks = 0; ks < 4; ++ks)
#pragma unroll
      for (int mf = 0; mf < 2; ++mf)
#pragma unroll
        for (int nf = 0; nf < 2; ++nf)
          acc[mf][nf] = __builtin_amdgcn_mfma_f32_16x16x32_bf16(af[mf][ks], bfv[nf][ks], acc[mf][nf], 0, 0, 0);
    __syncthreads();
    buf ^= 1;
  }
  // epilogue: m = mt*64 + w*32 + mf*16 + lg*4 + r ; n = nt*32 + nf*16 + lr
#pragma unroll
  for (int mf = 0; mf < 2; ++mf) {
    int mbase = mt * 64 + w * 32 + mf * 16 + lg * 4;
#pragma unroll
    for (int nf = 0; nf < 2; ++nf) {
      int n = nt * 32 + nf * 16 + lr;
      int b = n >> 6, d = n & 63;
      if (mat == 0) {
#pragma unroll
        for (int r = 0; r < 4; ++r)
          Qb[((size_t)b * S + mbase + r) * D + d] = f2bf(acc[mf][nf][r]);
      } else {
        union { u16 s[4]; ushort4 v; } u;
#pragma unroll
        for (int r = 0; r < 4; ++r) u.s[r] = f2bf(acc[mf][nf][r]);
        *(ushort4*)&VTb[((size_t)b * D + d) * S + mbase] = u.v;
      }
    }
  }
}

// ---- N3: column sums Z_j = sum_{i>=j, sc>1} exp(sc*SCL) (no-max: bounded).
__global__ __launch_bounds__(256) void k_stats(
    const u16* __restrict__ xb, const u16* __restrict__ Qb,
    float* __restrict__ rzbuf) {
  __shared__ float zs[4][16];
  int jg = blockIdx.x, b = blockIdx.y;
  int tid = threadIdx.x;
  int w = tid >> 6, l = tid & 63;
  int lr = l & 15, lg = l >> 4;
  int j0 = jg * 16;
  const u16* xbase = xb + (size_t)b * S * D;
  const u16* qbase = Qb + (size_t)b * S * D;
  bf16x8 xa0 = *(const bf16x8*)(xbase + (size_t)(j0 + lr) * D + lg * 8);
  bf16x8 xa1 = *(const bf16x8*)(xbase + (size_t)(j0 + lr) * D + 32 + lg * 8);
  float z[4] = {0.f, 0.f, 0.f, 0.f};
  for (int i16 = j0 + w * 16; i16 < S; i16 += 64) {
    bf16x8 q0 = *(const bf16x8*)(qbase + (size_t)(i16 + lr) * D + lg * 8);
    bf16x8 q1 = *(const bf16x8*)(qbase + (size_t)(i16 + lr) * D + 32 + lg * 8);
    f32x4 c = {};
    c = __builtin_amdgcn_mfma_f32_16x16x32_bf16(xa0, q0, c, 0, 0, 0);
    c = __builtin_amdgcn_mfma_f32_16x16x32_bf16(xa1, q1, c, 0, 0, 0);
    int i = i16 + lr;
#pragma unroll
    for (int r = 0; r < 4; ++r) {
      int j = j0 + lg * 4 + r;
      float sc = c[r];
      z[r] += (i >= j && sc > 1.0f) ? __expf(sc * SCL) : 0.f;
    }
  }
#pragma unroll
  for (int r = 0; r < 4; ++r) {
    z[r] += __shfl_xor(z[r], 1);
    z[r] += __shfl_xor(z[r], 2);
    z[r] += __shfl_xor(z[r], 4);
    z[r] += __shfl_xor(z[r], 8);
  }
  if (lr == 0) {
#pragma unroll
    for (int r = 0; r < 4; ++r) zs[w][lg * 4 + r] = z[r];
  }
  __syncthreads();
  if (tid < 16) {
    float zf = zs[0][tid] + zs[1][tid] + zs[2][tid] + zs[3][tid];
    rzbuf[(size_t)b * S + j0 + tid] = 1.0f / zf;
  }
}

// ---- N4: out += P_chunk @ V_chunk; P_ij = exp(sc*SCL)/Z_j (or 0).
// Reversed decode: heavy i-tiles dispatch first.
__global__ __launch_bounds__(256) void k_out(
    const u16* __restrict__ xb, const u16* __restrict__ Qb, const u16* __restrict__ VTb,
    const float* __restrict__ rzbuf, float* __restrict__ out) {
  __shared__ u16 Plds[4][16][72];
  int bx = 143 - blockIdx.x, b = blockIdx.y;   // heavy-first
  int it = 0, jc = 0, base = 0;
  for (int tt = 0; tt < 32; ++tt) {
    int nc = (tt + 4) >> 2;
    if (bx < base + nc) { it = tt; jc = bx - base; break; }
    base += nc;
  }
  int w = threadIdx.x >> 6, l = threadIdx.x & 63;
  int lr = l & 15, lg = l >> 4;
  int i0 = it * 64 + w * 16;
  const u16* xbase = xb + (size_t)b * S * D;
  const u16* qbase = Qb + (size_t)b * S * D;
  const u16* vbase = VTb + (size_t)b * D * S;
  const float* rzb = rzbuf + (size_t)b * S;
  bf16x8 qa0 = *(const bf16x8*)(qbase + (size_t)(i0 + lr) * D + lg * 8);
  bf16x8 qa1 = *(const bf16x8*)(qbase + (size_t)(i0 + lr) * D + 32 + lg * 8);
  f32x4 acc[4] = {};
  int jt_end = min(jc * 4 + 4, it + 1);
  for (int jt = jc * 4; jt < jt_end; ++jt) {
#pragma unroll
    for (int js = 0; js < 4; ++js) {
      int j16 = jt * 64 + js * 16;
      bf16x8 xb0 = *(const bf16x8*)(xbase + (size_t)(j16 + lr) * D + lg * 8);
      bf16x8 xb1 = *(const bf16x8*)(xbase + (size_t)(j16 + lr) * D + 32 + lg * 8);
      f32x4 c = {};
      c = __builtin_amdgcn_mfma_f32_16x16x32_bf16(qa0, xb0, c, 0, 0, 0);
      c = __builtin_amdgcn_mfma_f32_16x16x32_bf16(qa1, xb1, c, 0, 0, 0);
      int j = j16 + lr;
      float rzj = rzb[j];
#pragma unroll
      for (int r = 0; r < 4; ++r) {
        int i = i0 + lg * 4 + r;
        float sc = c[r];
        float wgt = (j <= i && sc > 1.0f) ? __expf(sc * SCL) * rzj : 0.f;
        Plds[w][lg * 4 + r][js * 16 + lr] = f2bf(wgt);
      }
    }
    asm volatile("s_waitcnt lgkmcnt(0)" ::: "memory");
#pragma unroll
    for (int kk = 0; kk < 2; ++kk) {
      bf16x8 pa = *(const bf16x8*)(&Plds[w][lr][kk * 32 + lg * 8]);
#pragma unroll
      for (int dt = 0; dt < 4; ++dt) {
        bf16x8 vbf = *(const bf16x8*)(vbase + (size_t)(dt * 16 + lr) * S + jt * 64 + kk * 32 + lg * 8);
        acc[dt] = __builtin_amdgcn_mfma_f32_16x16x32_bf16(pa, vbf, acc[dt], 0, 0, 0);
      }
    }
    asm volatile("s_waitcnt lgkmcnt(0)" ::: "memory");
  }
  float* obase = out + (size_t)b * S * D;
#pragma unroll
  for (int dt = 0; dt < 4; ++dt)
#pragma unroll
    for (int r = 0; r < 4; ++r) {
      int i = i0 + lg * 4 + r;
      atomicAdd(&obase[(size_t)i * D + dt * 16 + lr], acc[dt][r]);
    }
}

extern "C" void kernel_launch(void* const* d_in, const int* in_sizes, int n_in,
                              void* d_out, int out_size, void* d_ws, size_t ws_size,
                              hipStream_t stream) {
  const float* x  = (const float*)d_in[0];
  const float* wq = (const float*)d_in[1];
  const float* wv = (const float*)d_in[2];
  float* out = (float*)d_out;
  char* ws = (char*)d_ws;
  size_t off = 0;
  auto alloc = [&](size_t bytes) -> void* {
    void* p = ws + off; off += (bytes + 255) & ~255ULL; return p;
  };
  u16* xb   = (u16*)alloc((size_t)BATCH * S * D * 2);
  u16* xTb  = (u16*)alloc((size_t)BATCH * S * D * 2);
  u16* Qb   = (u16*)alloc((size_t)BATCH * S * D * 2);
  u16* VTb  = (u16*)alloc((size_t)BATCH * S * D * 2);
  float* rzbuf = (float*)alloc((size_t)BATCH * S * 4);
  u16* wqp  = (u16*)alloc((size_t)S * S * 2);   // W' = W_Q @ L (suffix-scanned)
  u16* wvb  = (u16*)alloc((size_t)S * S * 2);

  k_pre<<<3200, 256, 0, stream>>>(x, wq, wv, wqp, wvb, xb, xTb, out);
  k_wg<<<512, 128, 0, stream>>>(wqp, wvb, xTb, Qb, VTb);
  k_stats<<<dim3(128, BATCH), 256, 0, stream>>>(xb, Qb, rzbuf);
  k_out<<<dim3(144, BATCH), 256, 0, stream>>>(xb, Qb, VTb, rzbuf, out);
}